// Round 1
// baseline (201.613 us; speedup 1.0000x reference)
//
#include <hip/hip_runtime.h>
#include <hip/hip_bf16.h>

#define NQ 4096
#define NS 16384
#define DIM 128
#define NC 64
#define INFV 1000.0f

using bf16 = __hip_bfloat16;
typedef __attribute__((ext_vector_type(8))) short frag_ab;   // 8 bf16 = 4 VGPRs
typedef __attribute__((ext_vector_type(4))) float frag_cd;   // 4 fp32 acc

// ---------------------------------------------------------------- init
__global__ void k_init(float* __restrict__ summed, int* __restrict__ counts,
                       float* __restrict__ out) {
    int gid = blockIdx.x * blockDim.x + threadIdx.x;
    int stride = gridDim.x * blockDim.x;
    for (int i = gid; i < NQ * NC; i += stride) summed[i] = 0.f;
    if (gid < NC) counts[gid] = 0;
    if (gid == 0) out[0] = 0.f;
}

// ---------------------------------------------------------------- class histogram
__global__ void k_hist(const int* __restrict__ ys, int* __restrict__ counts) {
    int j = blockIdx.x * 256 + threadIdx.x;
    if (j < NS) atomicAdd(&counts[ys[j]], 1);
}

// ---------------------------------------------------------------- exclusive scan (C=64, 1 wave)
__global__ void k_scan(const int* __restrict__ counts, int* __restrict__ cursor,
                       int* __restrict__ offsets) {
    int t = threadIdx.x;  // 0..63
    int off = 0;
    for (int c = 0; c < t; ++c) off += counts[c];
    cursor[t] = off;
    offsets[t] = off;
}

// ---------------------------------------------------------------- scatter support indices by class
__global__ void k_scatter(const int* __restrict__ ys, int* __restrict__ cursor,
                          int* __restrict__ order, int* __restrict__ ysrt) {
    int j = blockIdx.x * 256 + threadIdx.x;
    if (j < NS) {
        int c = ys[j];
        int r = atomicAdd(&cursor[c], 1);
        order[r] = j;
        ysrt[r] = c;
    }
}

// ---------------------------------------------------------------- bf16 cast + gather (sorted) + sq-norms
// one wave per row; rows [0,NS): sorted xs; rows [NS,NS+NQ): xq
__global__ __launch_bounds__(256) void k_rows(
    const float* __restrict__ xs, const float* __restrict__ xq,
    const int* __restrict__ order, bf16* __restrict__ xsb, bf16* __restrict__ xqb,
    float* __restrict__ sqs, float* __restrict__ sqq) {
    int wave = threadIdx.x >> 6, lane = threadIdx.x & 63;
    int row = blockIdx.x * 4 + wave;
    const float* src;
    bf16* dst;
    float* sqdst;
    if (row < NS) {
        int s = order[row];
        src = xs + (size_t)s * DIM;
        dst = xsb + (size_t)row * DIM;
        sqdst = sqs + row;
    } else {
        int r2 = row - NS;
        src = xq + (size_t)r2 * DIM;
        dst = xqb + (size_t)r2 * DIM;
        sqdst = sqq + r2;
    }
    float2 v = *(const float2*)(src + lane * 2);
    __hip_bfloat162 h2;
    h2.x = __float2bfloat16(v.x);
    h2.y = __float2bfloat16(v.y);
    *(__hip_bfloat162*)(dst + lane * 2) = h2;
    float sq = v.x * v.x + v.y * v.y;
#pragma unroll
    for (int m = 1; m < 64; m <<= 1) sq += __shfl_xor(sq, m, 64);
    if (lane == 0) *sqdst = sq;
}

// ---------------------------------------------------------------- per-class prototype sums (fp32)
__global__ void k_mus(const float* __restrict__ xs, const int* __restrict__ order,
                      const int* __restrict__ offsets, const int* __restrict__ counts,
                      float* __restrict__ mus) {
    int c = blockIdx.x, d = threadIdx.x;  // 64 blocks x 128 threads
    int o = offsets[c], n = counts[c];
    float s = 0.f;
#pragma unroll 8
    for (int r = 0; r < n; ++r) {
        int src = order[o + r];
        s += xs[(size_t)src * DIM + d];
    }
    mus[c * DIM + d] = s;
}

// ---------------------------------------------------------------- main: GEMM + relu-logit + class row-sums
// grid (64 query-tiles, 16 support-splits) x 256 threads (4 waves)
// block: 64 queries x 1024 sorted support rows; class blocks are 256-aligned,
// so every 64-row tile is single-class.
__global__ __launch_bounds__(256) void k_main(
    const bf16* __restrict__ xqb, const bf16* __restrict__ xsb,
    const float* __restrict__ sqq, const float* __restrict__ sqs,
    const int* __restrict__ ysrt, float* __restrict__ summed) {
    __shared__ short Bsh[64][136];  // 272B row stride: 16B-aligned, 2-way bank alias (free)
    __shared__ float sqs_sh[64];

    const int tid = threadIdx.x;
    const int wave = tid >> 6, lane = tid & 63;
    const int quad = lane >> 4, l15 = lane & 15;
    const int qbase = blockIdx.x * 64, jbase = blockIdx.y * 1024;

    // A-frags: wave owns 16 query rows; lane holds row l15, k = quad*8 + j (+32 per kk)
    frag_ab afr[4];
    {
        const short* src =
            (const short*)xqb + (size_t)(qbase + wave * 16 + l15) * DIM + quad * 8;
#pragma unroll
        for (int kk = 0; kk < 4; ++kk) afr[kk] = *(const frag_ab*)(src + kk * 32);
    }
    // C-layout rows this lane owns: q = qbase + wave*16 + quad*4 + r
    float sqq_r[4];
#pragma unroll
    for (int r = 0; r < 4; ++r) sqq_r[r] = sqq[qbase + wave * 16 + quad * 4 + r];

    float rowsum[4] = {0.f, 0.f, 0.f, 0.f};
    int cur_cls = ysrt[jbase];

    for (int jt = 0; jt < 16; ++jt) {
        const int j0 = jbase + jt * 64;
        __syncthreads();
        // stage 64x128 bf16 tile: 1024 x 16B chunks, 4 per thread, coalesced
#pragma unroll
        for (int k = 0; k < 4; ++k) {
            int id = tid + k * 256;
            int row = id >> 4, col = id & 15;
            uint4 v = *(const uint4*)((const short*)xsb + (size_t)(j0 + row) * DIM + col * 8);
            *(uint4*)(&Bsh[row][col * 8]) = v;
        }
        if (tid < 64) sqs_sh[tid] = sqs[j0 + tid];
        __syncthreads();

        int tile_cls = ysrt[j0];
        if (tile_cls != cur_cls) {  // flush previous class (uniform across block)
#pragma unroll
            for (int r = 0; r < 4; ++r) {
                float v = rowsum[r];
                v += __shfl_xor(v, 1, 64);
                v += __shfl_xor(v, 2, 64);
                v += __shfl_xor(v, 4, 64);
                v += __shfl_xor(v, 8, 64);
                if (l15 == 0)
                    atomicAdd(&summed[(size_t)(qbase + wave * 16 + quad * 4 + r) * NC + cur_cls],
                              -0.5f * v);
                rowsum[r] = 0.f;
            }
            cur_cls = tile_cls;
        }

#pragma unroll
        for (int ct = 0; ct < 4; ++ct) {
            frag_cd acc = {0.f, 0.f, 0.f, 0.f};
            const short* brow = &Bsh[ct * 16 + l15][quad * 8];
#pragma unroll
            for (int kk = 0; kk < 4; ++kk) {
                frag_ab bfr = *(const frag_ab*)(brow + kk * 32);
                acc = __builtin_amdgcn_mfma_f32_16x16x32_bf16(afr[kk], bfr, acc, 0, 0, 0);
            }
            float sj = sqs_sh[ct * 16 + l15];
#pragma unroll
            for (int r = 0; r < 4; ++r) {
                float t = sqq_r[r] + sj - 2.f * acc[r];
                rowsum[r] += fmaxf(t, 0.f);  // accumulate relu; -0.5 applied at flush
            }
        }
    }
    // final flush
#pragma unroll
    for (int r = 0; r < 4; ++r) {
        float v = rowsum[r];
        v += __shfl_xor(v, 1, 64);
        v += __shfl_xor(v, 2, 64);
        v += __shfl_xor(v, 4, 64);
        v += __shfl_xor(v, 8, 64);
        if (l15 == 0)
            atomicAdd(&summed[(size_t)(qbase + wave * 16 + quad * 4 + r) * NC + cur_cls],
                      -0.5f * v);
    }
}

// ---------------------------------------------------------------- per-query: pos fixup + logsumexp
// one wave per query; lane doubles as (dim-pair index) in phase A and (class) in phase B
__global__ __launch_bounds__(256) void k_final(
    const float* __restrict__ xq, const int* __restrict__ yq,
    const float* __restrict__ xs, const int* __restrict__ ys,
    const int* __restrict__ pos, const int* __restrict__ counts,
    const float* __restrict__ mus, const float* __restrict__ summed,
    float* __restrict__ perq) {
    int wave = threadIdx.x >> 6, lane = threadIdx.x & 63;
    int i = blockIdx.x * 4 + wave;
    if (i >= NQ) return;
    int pi = pos[i];
    int yqi = yq[i];
    int cp = ys[pi];                      // class of the pos support row
    float cnt_p = (float)counts[cp];      // denom uses counts[ys[pos]]
    float cnt_yq = (float)counts[yqi];    // idx uses counts[yq]
    bool idx = cnt_yq > 1.f;
    float denom = fmaxf(cnt_p - 1.f, 0.1f);

    float2 q2 = *(const float2*)(xq + (size_t)i * DIM + lane * 2);
    float2 s2 = *(const float2*)(xs + (size_t)pi * DIM + lane * 2);
    float2 m2 = *(const float2*)(mus + (size_t)cp * DIM + lane * 2);

    float dot = q2.x * s2.x + q2.y * s2.y;
    float sqn_q = q2.x * q2.x + q2.y * q2.y;
    float sqn_s = s2.x * s2.x + s2.y * s2.y;
    float px = (m2.x - q2.x) / denom, py = (m2.y - q2.y) / denom;
    float dx = q2.x - px, dy = q2.y - py;
    float dd = dx * dx + dy * dy;
#pragma unroll
    for (int m = 1; m < 64; m <<= 1) {
        dot += __shfl_xor(dot, m, 64);
        sqn_q += __shfl_xor(sqn_q, m, 64);
        sqn_s += __shfl_xor(sqn_s, m, 64);
        dd += __shfl_xor(dd, m, 64);
    }
    float pos_logit = -sqrtf(fmaxf(dd, 0.f));
    float logit_pos = -0.5f * fmaxf(sqn_q + sqn_s - 2.f * dot, 0.f);
    float corr = (idx ? -INFV : 0.f) - logit_pos;  // replace pos entry's contribution

    // phase B: lane = class (NC == 64)
    float v = summed[(size_t)i * NC + lane];
    if (lane == cp) v += corr;
    float cnt_c = (float)counts[lane];
    v = v / (cnt_c - 1.f);
    float mx = v;
#pragma unroll
    for (int m = 1; m < 64; m <<= 1) mx = fmaxf(mx, __shfl_xor(mx, m, 64));
    float e = __expf(v - mx);
#pragma unroll
    for (int m = 1; m < 64; m <<= 1) e += __shfl_xor(e, m, 64);
    float neg = mx + __logf(e);
    if (lane == 0) perq[i] = neg - pos_logit;
}

// ---------------------------------------------------------------- mean over queries
__global__ void k_reduce(const float* __restrict__ perq, float* __restrict__ out) {
    int tid = threadIdx.x;  // 256 threads
    float s = 0.f;
    for (int i = tid; i < NQ; i += 256) s += perq[i];
#pragma unroll
    for (int m = 1; m < 64; m <<= 1) s += __shfl_xor(s, m, 64);
    __shared__ float smem[4];
    if ((tid & 63) == 0) smem[tid >> 6] = s;
    __syncthreads();
    if (tid == 0) out[0] = (smem[0] + smem[1] + smem[2] + smem[3]) * (1.f / NQ);
}

// ---------------------------------------------------------------- launcher
extern "C" void kernel_launch(void* const* d_in, const int* in_sizes, int n_in,
                              void* d_out, int out_size, void* d_ws, size_t ws_size,
                              hipStream_t stream) {
    const float* xq = (const float*)d_in[0];
    const int* yq = (const int*)d_in[1];
    const float* xs = (const float*)d_in[2];
    const int* ys = (const int*)d_in[3];
    const int* pos = (const int*)d_in[4];
    float* out = (float*)d_out;

    char* w = (char*)d_ws;
    float* summed = (float*)w;  w += (size_t)NQ * NC * 4;   // 1 MB
    float* mus    = (float*)w;  w += (size_t)NC * DIM * 4;  // 32 KB
    int* counts   = (int*)w;    w += 256;
    int* cursor   = (int*)w;    w += 256;
    int* offsets  = (int*)w;    w += 256;
    int* order    = (int*)w;    w += (size_t)NS * 4;        // 64 KB
    int* ysrt     = (int*)w;    w += (size_t)NS * 4;        // 64 KB
    bf16* xsb     = (bf16*)w;   w += (size_t)NS * DIM * 2;  // 4 MB (sorted)
    bf16* xqb     = (bf16*)w;   w += (size_t)NQ * DIM * 2;  // 1 MB
    float* sqs    = (float*)w;  w += (size_t)NS * 4;        // sorted order
    float* sqq    = (float*)w;  w += (size_t)NQ * 4;
    float* perq   = (float*)w;  w += (size_t)NQ * 4;

    k_init<<<256, 256, 0, stream>>>(summed, counts, out);
    k_hist<<<NS / 256, 256, 0, stream>>>(ys, counts);
    k_scan<<<1, 64, 0, stream>>>(counts, cursor, offsets);
    k_scatter<<<NS / 256, 256, 0, stream>>>(ys, cursor, order, ysrt);
    k_rows<<<(NS + NQ) / 4, 256, 0, stream>>>(xs, xq, order, xsb, xqb, sqs, sqq);
    k_mus<<<NC, DIM, 0, stream>>>(xs, order, offsets, counts, mus);
    k_main<<<dim3(NQ / 64, NS / 1024), 256, 0, stream>>>(xqb, xsb, sqq, sqs, ysrt, summed);
    k_final<<<NQ / 4, 256, 0, stream>>>(xq, yq, xs, ys, pos, counts, mus, summed, perq);
    k_reduce<<<1, 256, 0, stream>>>(perq, out);
}